// Round 1
// baseline (176.513 us; speedup 1.0000x reference)
//
#include <hip/hip_runtime.h>
#include <hip/hip_bf16.h>
#include <math.h>

#define C 64
#define B 8
#define HW 65536   // 256*256
#define NMID 17
#define NEXP 4
#define TEMP 34.0f

// ---------------- Kernel 1: global average pool per (b,c) plane ----------------
__global__ __launch_bounds__(256) void pool_kernel(const float* __restrict__ x,
                                                   float* __restrict__ pooled) {
    const int plane = blockIdx.x;                       // 0..511  == b*64 + c
    const float4* xp = (const float4*)(x + (size_t)plane * HW);
    float s = 0.0f;
    for (int it = threadIdx.x; it < HW / 4; it += 256) {
        float4 v = xp[it];
        s += (v.x + v.y) + (v.z + v.w);
    }
    // wave64 reduce
    #pragma unroll
    for (int off = 32; off > 0; off >>= 1) s += __shfl_down(s, off);
    __shared__ float wsum[4];
    const int wid = threadIdx.x >> 6;
    if ((threadIdx.x & 63) == 0) wsum[wid] = s;
    __syncthreads();
    if (threadIdx.x == 0) {
        float t = (wsum[0] + wsum[1]) + (wsum[2] + wsum[3]);
        pooled[plane] = t * (1.0f / (float)HW);
    }
}

// ---------------- Kernel 2: MLP -> softmax -> mixed W (transposed) + bias ------
__global__ __launch_bounds__(256) void mix_kernel(const float* __restrict__ pooled,
                                                  const float* __restrict__ fc1_w,
                                                  const float* __restrict__ fc2_w,
                                                  const float* __restrict__ fc2_b,
                                                  const float* __restrict__ ew,
                                                  const float* __restrict__ eb,
                                                  float* __restrict__ wt,     // [B][C_in][C_out]
                                                  float* __restrict__ bmix) { // [B][C_out]
    __shared__ float attn_s[B][NEXP];
    const int tid = threadIdx.x;
    if (tid < B) {
        const int b = tid;
        float h[NMID];
        #pragma unroll
        for (int m = 0; m < NMID; ++m) {
            float s = 0.0f;
            for (int c = 0; c < C; ++c) s += pooled[b * C + c] * fc1_w[m * C + c];
            h[m] = fmaxf(s, 0.0f);
        }
        float lg[NEXP];
        float mx = -1e30f;
        #pragma unroll
        for (int e = 0; e < NEXP; ++e) {
            float s = fc2_b[e];
            for (int m = 0; m < NMID; ++m) s += h[m] * fc2_w[e * NMID + m];
            lg[e] = s * (1.0f / TEMP);
            mx = fmaxf(mx, lg[e]);
        }
        float den = 0.0f;
        #pragma unroll
        for (int e = 0; e < NEXP; ++e) { lg[e] = expf(lg[e] - mx); den += lg[e]; }
        float inv = 1.0f / den;
        #pragma unroll
        for (int e = 0; e < NEXP; ++e) attn_s[b][e] = lg[e] * inv;
    }
    __syncthreads();
    // mixed weights, stored i-major: wt[b*4096 + i*64 + o] = sum_e attn[b][e]*ew[e,o,i]
    for (int idx = tid; idx < B * C * C; idx += 256) {
        const int b = idx >> 12;
        const int rem = idx & 4095;
        const int i = rem >> 6;
        const int o = rem & 63;
        float s = 0.0f;
        #pragma unroll
        for (int e = 0; e < NEXP; ++e) s += attn_s[b][e] * ew[e * (C * C) + o * C + i];
        wt[idx] = s;
    }
    for (int idx = tid; idx < B * C; idx += 256) {
        const int b = idx >> 6;
        const int o = idx & 63;
        float s = 0.0f;
        #pragma unroll
        for (int e = 0; e < NEXP; ++e) s += attn_s[b][e] * eb[e * C + o];
        bmix[idx] = s;
    }
}

// ---------------- Kernel 3: per-sample 1x1 conv (64->64) ----------------------
// out[b,o,p] = sum_i wt[b][i][o] * x[b,i,p] + bias[b,o]
// One pixel per thread; W rows are wave-uniform -> scalar loads -> v_fmac with
// SGPR operand; x loads and out stores are dword-coalesced per channel.
__global__ __launch_bounds__(256) void conv_kernel(const float* __restrict__ x,
                                                   const float* __restrict__ wt,
                                                   const float* __restrict__ bias,
                                                   float* __restrict__ out) {
    const int b = blockIdx.y;
    const int p = blockIdx.x * 256 + threadIdx.x;
    const float* __restrict__ xb = x + (size_t)b * C * HW + p;
    const float* __restrict__ Wb = wt + b * (C * C);
    const float* __restrict__ Bb = bias + b * C;

    float acc[C];
    #pragma unroll
    for (int o = 0; o < C; ++o) acc[o] = Bb[o];

    #pragma unroll 4
    for (int i = 0; i < C; ++i) {
        const float xi = xb[(size_t)i * HW];
        const float* __restrict__ wrow = Wb + i * C;   // uniform, contiguous 256B
        #pragma unroll
        for (int o = 0; o < C; ++o) acc[o] = fmaf(wrow[o], xi, acc[o]);
    }

    float* __restrict__ ob = out + (size_t)b * C * HW + p;
    #pragma unroll
    for (int o = 0; o < C; ++o) ob[(size_t)o * HW] = acc[o];
}

extern "C" void kernel_launch(void* const* d_in, const int* in_sizes, int n_in,
                              void* d_out, int out_size, void* d_ws, size_t ws_size,
                              hipStream_t stream) {
    const float* x     = (const float*)d_in[0];
    const float* fc1_w = (const float*)d_in[1];
    const float* fc2_w = (const float*)d_in[2];
    const float* fc2_b = (const float*)d_in[3];
    const float* ew    = (const float*)d_in[4];
    const float* eb    = (const float*)d_in[5];
    float* out = (float*)d_out;

    // workspace layout (floats): pooled[512] | wt[8*64*64] | bmix[8*64]
    float* ws     = (float*)d_ws;
    float* pooled = ws;
    float* wt     = ws + B * C;
    float* bmix   = wt + B * C * C;

    pool_kernel<<<dim3(B * C), dim3(256), 0, stream>>>(x, pooled);
    mix_kernel<<<dim3(1), dim3(256), 0, stream>>>(pooled, fc1_w, fc2_w, fc2_b, ew, eb, wt, bmix);
    conv_kernel<<<dim3(HW / 256, B), dim3(256), 0, stream>>>(x, wt, bmix, out);
}

// Round 2
// 94.261 us; speedup vs baseline: 1.8726x; 1.8726x over previous
//
#include <hip/hip_runtime.h>
#include <hip/hip_bf16.h>
#include <math.h>

#define C 64
#define B 8
#define HW 65536   // 256*256
#define NMID 17
#define NEXP 4
#define TEMP 34.0f

// ---------------- Kernel 1: global average pool per (b,c) plane ----------------
__global__ __launch_bounds__(256) void pool_kernel(const float* __restrict__ x,
                                                   float* __restrict__ pooled) {
    const int plane = blockIdx.x;                       // 0..511  == b*64 + c
    const float4* xp = (const float4*)(x + (size_t)plane * HW);
    float s = 0.0f;
    #pragma unroll 4
    for (int it = threadIdx.x; it < HW / 4; it += 256) {
        float4 v = xp[it];
        s += (v.x + v.y) + (v.z + v.w);
    }
    // wave64 reduce
    #pragma unroll
    for (int off = 32; off > 0; off >>= 1) s += __shfl_down(s, off);
    __shared__ float wsum[4];
    const int wid = threadIdx.x >> 6;
    if ((threadIdx.x & 63) == 0) wsum[wid] = s;
    __syncthreads();
    if (threadIdx.x == 0) {
        float t = (wsum[0] + wsum[1]) + (wsum[2] + wsum[3]);
        pooled[plane] = t * (1.0f / (float)HW);
    }
}

// ------- Kernel 2: per-sample attention (MLP+softmax) + weight/bias mix --------
// One block per batch sample b. Parallel fc1 (17 threads), fc2 (4 threads),
// softmax (thread 0), then all 256 threads mix the 4096-entry weight tile.
__global__ __launch_bounds__(256) void attn_mix_kernel(const float* __restrict__ pooled,
                                                       const float* __restrict__ fc1_w,
                                                       const float* __restrict__ fc2_w,
                                                       const float* __restrict__ fc2_b,
                                                       const float* __restrict__ ew,
                                                       const float* __restrict__ eb,
                                                       float* __restrict__ wt,     // [B][C_in][C_out]
                                                       float* __restrict__ bmix) { // [B][C_out]
    const int b = blockIdx.x;
    const int tid = threadIdx.x;
    __shared__ float pooled_s[C];
    __shared__ float h_s[NMID];
    __shared__ float lg_s[NEXP];
    __shared__ float attn_s[NEXP];

    if (tid < C) pooled_s[tid] = pooled[b * C + tid];
    __syncthreads();

    if (tid < NMID) {
        float s = 0.0f;
        #pragma unroll
        for (int c = 0; c < C; ++c) s += pooled_s[c] * fc1_w[tid * C + c];
        h_s[tid] = fmaxf(s, 0.0f);
    }
    __syncthreads();

    if (tid < NEXP) {
        float s = fc2_b[tid];
        #pragma unroll
        for (int m = 0; m < NMID; ++m) s += h_s[m] * fc2_w[tid * NMID + m];
        lg_s[tid] = s * (1.0f / TEMP);
    }
    __syncthreads();

    if (tid == 0) {
        float mx = fmaxf(fmaxf(lg_s[0], lg_s[1]), fmaxf(lg_s[2], lg_s[3]));
        float e0 = expf(lg_s[0] - mx);
        float e1 = expf(lg_s[1] - mx);
        float e2 = expf(lg_s[2] - mx);
        float e3 = expf(lg_s[3] - mx);
        float inv = 1.0f / (e0 + e1 + e2 + e3);
        attn_s[0] = e0 * inv; attn_s[1] = e1 * inv;
        attn_s[2] = e2 * inv; attn_s[3] = e3 * inv;
    }
    __syncthreads();

    const float a0 = attn_s[0], a1 = attn_s[1], a2 = attn_s[2], a3 = attn_s[3];

    // wt[b][i][o] = sum_e attn[e] * ew[e,o,i]; writes coalesced (idx = i*64+o),
    // ew reads stride-64 but only 64 KB total -> L2 after first touch.
    #pragma unroll
    for (int k = 0; k < (C * C) / 256; ++k) {
        const int idx = k * 256 + tid;
        const int i = idx >> 6;
        const int o = idx & 63;
        const int t = o * C + i;
        float s = a0 * ew[0 * C * C + t] + a1 * ew[1 * C * C + t]
                + a2 * ew[2 * C * C + t] + a3 * ew[3 * C * C + t];
        wt[b * C * C + idx] = s;
    }
    if (tid < C) {
        float s = a0 * eb[0 * C + tid] + a1 * eb[1 * C + tid]
                + a2 * eb[2 * C + tid] + a3 * eb[3 * C + tid];
        bmix[b * C + tid] = s;
    }
}

// ---------------- Kernel 3: per-sample 1x1 conv (64->64) ----------------------
// out[b,o,p] = sum_i wt[b][i][o] * x[b,i,p] + bias[b,o]
// One pixel per thread; W rows are wave-uniform -> scalar loads -> v_fmac with
// SGPR operand; x loads and out stores are dword-coalesced per channel.
__global__ __launch_bounds__(256) void conv_kernel(const float* __restrict__ x,
                                                   const float* __restrict__ wt,
                                                   const float* __restrict__ bias,
                                                   float* __restrict__ out) {
    const int b = blockIdx.y;
    const int p = blockIdx.x * 256 + threadIdx.x;
    const float* __restrict__ xb = x + (size_t)b * C * HW + p;
    const float* __restrict__ Wb = wt + b * (C * C);
    const float* __restrict__ Bb = bias + b * C;

    float acc[C];
    #pragma unroll
    for (int o = 0; o < C; ++o) acc[o] = Bb[o];

    #pragma unroll 4
    for (int i = 0; i < C; ++i) {
        const float xi = xb[(size_t)i * HW];
        const float* __restrict__ wrow = Wb + i * C;   // uniform, contiguous 256B
        #pragma unroll
        for (int o = 0; o < C; ++o) acc[o] = fmaf(wrow[o], xi, acc[o]);
    }

    float* __restrict__ ob = out + (size_t)b * C * HW + p;
    #pragma unroll
    for (int o = 0; o < C; ++o) ob[(size_t)o * HW] = acc[o];
}

extern "C" void kernel_launch(void* const* d_in, const int* in_sizes, int n_in,
                              void* d_out, int out_size, void* d_ws, size_t ws_size,
                              hipStream_t stream) {
    const float* x     = (const float*)d_in[0];
    const float* fc1_w = (const float*)d_in[1];
    const float* fc2_w = (const float*)d_in[2];
    const float* fc2_b = (const float*)d_in[3];
    const float* ew    = (const float*)d_in[4];
    const float* eb    = (const float*)d_in[5];
    float* out = (float*)d_out;

    // workspace layout (floats): pooled[512] | wt[8*64*64] | bmix[8*64]
    float* ws     = (float*)d_ws;
    float* pooled = ws;
    float* wt     = ws + B * C;
    float* bmix   = wt + B * C * C;

    pool_kernel<<<dim3(B * C), dim3(256), 0, stream>>>(x, pooled);
    attn_mix_kernel<<<dim3(B), dim3(256), 0, stream>>>(pooled, fc1_w, fc2_w, fc2_b, ew, eb, wt, bmix);
    conv_kernel<<<dim3(HW / 256, B), dim3(256), 0, stream>>>(x, wt, bmix, out);
}